// Round 3
// baseline (400.865 us; speedup 1.0000x reference)
//
#include <hip/hip_runtime.h>
#include <hip/hip_bf16.h>
#include <cstdint>
#include <cstddef>

// BertMoE: B=4,S=2048,H=768,F=3072,E=8,K=2. tokens T=8192, pairs=16384.
#define T_TOK 8192
#define HDIM  768
#define FDIM  3072
#define NEXP  8

typedef __attribute__((ext_vector_type(8))) __bf16 bf16x8;
typedef __attribute__((ext_vector_type(4))) float  f32x4;

static __device__ __forceinline__ f32x4 mfma16(bf16x8 a, bf16x8 b, f32x4 c) {
  return __builtin_amdgcn_mfma_f32_16x16x32_bf16(a, b, c, 0, 0, 0);
}

static __device__ __forceinline__ unsigned short f2b(float f) {
  return __builtin_bit_cast(unsigned short, (__bf16)f);
}

static __device__ __forceinline__ void gload16(const void* g, void* l) {
  __builtin_amdgcn_global_load_lds(
      (const __attribute__((address_space(1))) void*)g,
      (__attribute__((address_space(3))) void*)l, 16, 0, 0);
}

// ---------------- workspace layout (bytes) ----------------
static constexpr size_t OFF_XB   = 0;                                        // T*H bf16
static constexpr size_t OFF_WIB  = OFF_XB  + (size_t)T_TOK * HDIM * 2;       // E*F*H bf16
static constexpr size_t OFF_WOB  = OFF_WIB + (size_t)NEXP * FDIM * HDIM * 2; // E*H*F bf16
static constexpr size_t OFF_HBUF = OFF_WOB + (size_t)NEXP * HDIM * FDIM * 2; // 2T*F bf16
static constexpr size_t OFF_META = OFF_HBUF + (size_t)2 * T_TOK * FDIM * 2;
static constexpr size_t OFF_TOKE = OFF_META + 256;
static constexpr size_t OFF_TOKW = OFF_TOKE + 65536;
static constexpr size_t OFF_PTOK = OFF_TOKW + 65536;
static constexpr size_t OFF_PW   = OFF_PTOK + 65536;
// stage [16384][768] f32 = 50.33 MB: ALIASES xb+wib (dead once gemmA is done)
static constexpr size_t OFF_STAGE = 0;

// ---------------- fp32 -> bf16 convert ----------------
__global__ __launch_bounds__(256) void cvt_kernel(const float* __restrict__ s,
                                                  unsigned short* __restrict__ d, int n4) {
  int i = blockIdx.x * 256 + threadIdx.x;
  int stride = gridDim.x * 256;
  for (; i < n4; i += stride) {
    float4 v = ((const float4*)s)[i];
    ushort4 o;
    o.x = f2b(v.x); o.y = f2b(v.y); o.z = f2b(v.z); o.w = f2b(v.w);
    ((ushort4*)d)[i] = o;
  }
}

// ---------------- router: logits, top2, softmax ----------------
__global__ __launch_bounds__(256) void router_kernel(const float* __restrict__ x,
                                                     const float* __restrict__ Wr,
                                                     int* __restrict__ tok_e,
                                                     float* __restrict__ tok_w) {
  __shared__ float wr[NEXP * HDIM];
  int tid = threadIdx.x;
  for (int i = tid; i < NEXP * HDIM; i += 256) wr[i] = Wr[i];
  __syncthreads();
  int lane = tid & 63;
  int wv = tid >> 6;
  int t = blockIdx.x * 4 + wv;
  const float* xr = x + (size_t)t * HDIM;
  float p[NEXP];
#pragma unroll
  for (int e = 0; e < NEXP; ++e) p[e] = 0.f;
  for (int j = 0; j < HDIM / 64; ++j) {
    float xv = xr[j * 64 + lane];
#pragma unroll
    for (int e = 0; e < NEXP; ++e) p[e] += xv * wr[e * HDIM + j * 64 + lane];
  }
#pragma unroll
  for (int e = 0; e < NEXP; ++e) {
    float v = p[e];
    for (int off = 32; off; off >>= 1) v += __shfl_xor(v, off);
    p[e] = v;
  }
  if (lane == 0) {
    float v0 = -1e30f, v1 = -1e30f; int i0 = 0, i1 = 0;
#pragma unroll
    for (int e = 0; e < NEXP; ++e) {
      float v = p[e];
      if (v > v0) { v1 = v0; i1 = i0; v0 = v; i0 = e; }
      else if (v > v1) { v1 = v; i1 = e; }
    }
    float ew = expf(v1 - v0);
    float w0 = 1.0f / (1.0f + ew);
    float w1 = ew * w0;
    tok_e[t * 2 + 0] = i0; tok_w[t * 2 + 0] = w0;
    tok_e[t * 2 + 1] = i1; tok_w[t * 2 + 1] = w1;
  }
}

// ---------------- count / scan / scatter ----------------
__global__ __launch_bounds__(256) void count_kernel(const int* __restrict__ tok_e,
                                                    int* __restrict__ counts) {
  __shared__ int h[NEXP];
  int tid = threadIdx.x;
  if (tid < NEXP) h[tid] = 0;
  __syncthreads();
  int i = blockIdx.x * 256 + tid;
  atomicAdd(&h[tok_e[i]], 1);
  __syncthreads();
  if (tid < NEXP && h[tid] > 0) atomicAdd(&counts[tid], h[tid]);
}

__global__ void scan_kernel(const int* __restrict__ counts, int* __restrict__ base) {
  if (threadIdx.x == 0 && blockIdx.x == 0) {
    int s = 0;
    for (int e = 0; e < NEXP; ++e) { base[e] = s; s += counts[e]; }
  }
}

__global__ __launch_bounds__(256) void scatter_kernel(const int* __restrict__ tok_e,
                                                      const float* __restrict__ tok_w,
                                                      const int* __restrict__ base,
                                                      int* __restrict__ cursor,
                                                      int* __restrict__ pair_tok,
                                                      float* __restrict__ pair_w) {
  __shared__ int h[NEXP], bstart[NEXP];
  int tid = threadIdx.x;
  if (tid < NEXP) h[tid] = 0;
  __syncthreads();
  int i = blockIdx.x * 256 + tid;
  int e = tok_e[i];
  int r = atomicAdd(&h[e], 1);
  __syncthreads();
  if (tid < NEXP) bstart[tid] = (h[tid] > 0) ? atomicAdd(&cursor[tid], h[tid]) : 0;
  __syncthreads();
  int pos = base[e] + bstart[e] + r;
  pair_tok[pos] = i;          // packed (tok<<1)|slot
  pair_w[pos] = tok_w[i];
}

// ================= gemmA: H = gelu(X * Wi^T + bi) -> hbuf (bf16) =================
// 256x256 tile, BK=64, 8 waves, 4-phase. 1-D grid, expert = bid&7 (XCD affinity).
__global__ __launch_bounds__(512, 2) void gemmA_kernel(
    const unsigned short* __restrict__ xb, const unsigned short* __restrict__ wib,
    const float* __restrict__ bi,
    const int* __restrict__ counts, const int* __restrict__ base,
    const int* __restrict__ pair_tok, unsigned short* __restrict__ hbuf) {
  const int bid = blockIdx.x;
  const int e = bid & 7;                 // expert pinned to XCD bid%8
  const int j = bid >> 3;                // 0..383
  const int mtq = j / 48;
  const int rem = j - mtq * 48;
  const int nt = rem >> 2;               // 0..11, 4 consecutive j share one B-panel
  const int mt = mtq * 4 + (rem & 3);    // A-panels cycle in L2-sized window
  const int ne = counts[e];
  if (mt * 256 >= ne) return;
  const int pb = base[e];
  constexpr int NT = HDIM / 64;          // 12

  extern __shared__ char smem[];         // 2 x (A 32KB | B 32KB) = 128 KB

  const int tid = threadIdx.x;
  const int lane = tid & 63;
  const int wv = tid >> 6;
  const int wm = wv >> 2;                // 0..1
  const int wn = wv & 3;                 // 0..3
  const int l15 = lane & 15;
  const int lkb = (lane >> 4) * 16;

  const int crow = tid >> 3;
  const int ck = tid & 7;
  const int swz = (ck ^ (crow & 7)) * 16;
  const char* aS[4]; const char* bS[4];
#pragma unroll
  for (int i = 0; i < 4; ++i) {
    int gr = mt * 256 + i * 64 + crow; if (gr > ne - 1) gr = ne - 1;
    int tok = pair_tok[pb + gr] >> 1;
    aS[i] = (const char*)xb + (size_t)tok * (HDIM * 2) + swz;
    int br = nt * 256 + i * 64 + crow;
    bS[i] = (const char*)wib + ((size_t)e * FDIM * HDIM + (size_t)br * HDIM) * 2 + swz;
  }

  auto STAGE = [&](int c, int t) {
    if (t < NT) {
      const char* src = (c < 4 ? aS[c] : bS[c - 4]) + t * 128;
      char* dst = smem + (size_t)((t & 1) * 65536 + c * 8192 + tid * 16);
      gload16(src, dst);
    }
  };

  bf16x8 aR[8], bR0[4], bR1[4];
  f32x4 acc[8][4];
#pragma unroll
  for (int mi = 0; mi < 8; ++mi)
#pragma unroll
    for (int ni = 0; ni < 4; ++ni) acc[mi][ni] = (f32x4){0.f, 0.f, 0.f, 0.f};

  auto READA = [&](int cb, int h) {
#pragma unroll
    for (int m2 = 0; m2 < 4; ++m2)
#pragma unroll
      for (int k2 = 0; k2 < 2; ++k2) {
        int lr = wm * 128 + (h * 4 + m2) * 16 + l15;
        int cbyte = k2 * 64 + lkb;
        aR[m2 * 2 + k2] =
            *(const bf16x8*)(smem + cb + lr * 128 + (cbyte ^ ((lr & 7) << 4)));
      }
  };
  auto READB = [&](int cb, int h, bf16x8* bR) {
#pragma unroll
    for (int n2 = 0; n2 < 2; ++n2)
#pragma unroll
      for (int k2 = 0; k2 < 2; ++k2) {
        int lr = wn * 64 + (h * 2 + n2) * 16 + l15;
        int cbyte = k2 * 64 + lkb;
        bR[n2 * 2 + k2] =
            *(const bf16x8*)(smem + cb + 32768 + lr * 128 + (cbyte ^ ((lr & 7) << 4)));
      }
  };
  auto MFMAQ = [&](int qm, int qn, const bf16x8* bR) {
#pragma unroll
    for (int m2 = 0; m2 < 4; ++m2)
#pragma unroll
      for (int n2 = 0; n2 < 2; ++n2)
#pragma unroll
        for (int k2 = 0; k2 < 2; ++k2)
          acc[qm * 4 + m2][qn * 2 + n2] =
              mfma16(aR[m2 * 2 + k2], bR[n2 * 2 + k2], acc[qm * 4 + m2][qn * 2 + n2]);
  };

#pragma unroll
  for (int c = 0; c < 8; ++c) STAGE(c, 0);
  STAGE(0, 1); STAGE(1, 1);
  asm volatile("s_waitcnt vmcnt(2)" ::: "memory");
  __builtin_amdgcn_s_barrier();

  for (int t = 0; t < NT; ++t) {
    const int cb = (t & 1) * 65536;
    READA(cb, 0); READB(cb, 0, bR0);
    STAGE(2, t + 1); STAGE(3, t + 1);
    __builtin_amdgcn_s_barrier();
    asm volatile("s_waitcnt lgkmcnt(0)" ::: "memory");
    __builtin_amdgcn_sched_barrier(0);
    __builtin_amdgcn_s_setprio(1);
    MFMAQ(0, 0, bR0);
    __builtin_amdgcn_s_setprio(0);
    __builtin_amdgcn_s_barrier();
    READB(cb, 1, bR1);
    STAGE(4, t + 1); STAGE(5, t + 1);
    __builtin_amdgcn_s_barrier();
    asm volatile("s_waitcnt lgkmcnt(0)" ::: "memory");
    __builtin_amdgcn_sched_barrier(0);
    __builtin_amdgcn_s_setprio(1);
    MFMAQ(0, 1, bR1);
    __builtin_amdgcn_s_setprio(0);
    __builtin_amdgcn_s_barrier();
    READA(cb, 1);
    STAGE(6, t + 1); STAGE(7, t + 1);
    __builtin_amdgcn_s_barrier();
    asm volatile("s_waitcnt lgkmcnt(0)" ::: "memory");
    __builtin_amdgcn_sched_barrier(0);
    __builtin_amdgcn_s_setprio(1);
    MFMAQ(1, 1, bR1);
    __builtin_amdgcn_s_setprio(0);
    __builtin_amdgcn_s_barrier();
    STAGE(0, t + 2); STAGE(1, t + 2);
    __builtin_amdgcn_s_barrier();
    __builtin_amdgcn_s_setprio(1);
    MFMAQ(1, 0, bR0);
    __builtin_amdgcn_s_setprio(0);
    if (t + 2 < NT) asm volatile("s_waitcnt vmcnt(2)" ::: "memory");
    else            asm volatile("s_waitcnt vmcnt(0)" ::: "memory");
    __builtin_amdgcn_s_barrier();
  }

  const float* be = bi + (size_t)e * FDIM;
  float bv[4];
#pragma unroll
  for (int ni = 0; ni < 4; ++ni) bv[ni] = be[nt * 256 + wn * 64 + ni * 16 + l15];
#pragma unroll
  for (int mi = 0; mi < 8; ++mi)
#pragma unroll
    for (int r = 0; r < 4; ++r) {
      int row = mt * 256 + wm * 128 + mi * 16 + (lane >> 4) * 4 + r;
      if (row < ne) {
        unsigned short* hr = hbuf + (size_t)(pb + row) * FDIM + nt * 256 + wn * 64 + l15;
#pragma unroll
        for (int ni = 0; ni < 4; ++ni) {
          float v = acc[mi][ni][r] + bv[ni];
          v = 0.5f * v * (1.0f + erff(v * 0.70710678118654752f));
          hr[ni * 16] = f2b(v);
        }
      }
    }
}

// ================= gemmB: stage = (H * Wo^T + bo) * w  (f32) =================
// 256x192 tile, BK=64, 8 waves (2x4, per-wave 128x48), 4-phase, 7 chunks/K-tile.
__global__ __launch_bounds__(512, 2) void gemmB_kernel(
    const unsigned short* __restrict__ hbuf, const unsigned short* __restrict__ wob,
    const float* __restrict__ bo,
    const int* __restrict__ counts, const int* __restrict__ base,
    const int* __restrict__ pair_tok, const float* __restrict__ pair_w,
    float* __restrict__ stage) {
  const int bid = blockIdx.x;
  const int e = bid & 7;
  const int j = bid >> 3;                // 0..127
  const int mt = j >> 2;
  const int nt = j & 3;                  // 4 consecutive j share one B-panel
  const int ne = counts[e];
  if (mt * 256 >= ne) return;
  const int pb = base[e];
  constexpr int NT = FDIM / 64;          // 48
  constexpr int BUFS = 57344;            // A 32KB + B 24KB

  extern __shared__ char smem[];         // 112 KB

  const int tid = threadIdx.x;
  const int lane = tid & 63;
  const int wv = tid >> 6;
  const int wm = wv >> 2;                // 0..1
  const int wn = wv & 3;                 // 0..3 (48-col bands)
  const int l15 = lane & 15;
  const int lkb = (lane >> 4) * 16;

  const int crow = tid >> 3;
  const int ck = tid & 7;
  const int swz = (ck ^ (crow & 7)) * 16;
  const char* aS[4]; const char* bS[3];
#pragma unroll
  for (int i = 0; i < 4; ++i) {
    int gr = mt * 256 + i * 64 + crow; if (gr > ne - 1) gr = ne - 1;
    aS[i] = (const char*)hbuf + (size_t)(pb + gr) * (FDIM * 2) + swz;
  }
#pragma unroll
  for (int i = 0; i < 3; ++i) {
    int br = nt * 192 + i * 64 + crow;
    bS[i] = (const char*)wob + ((size_t)e * HDIM * FDIM + (size_t)br * FDIM) * 2 + swz;
  }

  auto STAGE = [&](int c, int t) {       // c 0..3: A, 4..6: B
    if (t < NT) {
      const char* src = (c < 4 ? aS[c] : bS[c - 4]) + t * 128;
      char* dst = smem + (size_t)((t & 1) * BUFS +
                                  (c < 4 ? c * 8192 : 32768 + (c - 4) * 8192) + tid * 16);
      gload16(src, dst);
    }
  };

  bf16x8 aR[8], b01[4], b2[2];
  f32x4 acc[8][3];
#pragma unroll
  for (int mi = 0; mi < 8; ++mi)
#pragma unroll
    for (int ni = 0; ni < 3; ++ni) acc[mi][ni] = (f32x4){0.f, 0.f, 0.f, 0.f};

  auto READA = [&](int cb, int h) {
#pragma unroll
    for (int m2 = 0; m2 < 4; ++m2)
#pragma unroll
      for (int k2 = 0; k2 < 2; ++k2) {
        int lr = wm * 128 + (h * 4 + m2) * 16 + l15;
        int cbyte = k2 * 64 + lkb;
        aR[m2 * 2 + k2] =
            *(const bf16x8*)(smem + cb + lr * 128 + (cbyte ^ ((lr & 7) << 4)));
      }
  };
  auto READB01 = [&](int cb) {
#pragma unroll
    for (int n2 = 0; n2 < 2; ++n2)
#pragma unroll
      for (int k2 = 0; k2 < 2; ++k2) {
        int lr = wn * 48 + n2 * 16 + l15;
        int cbyte = k2 * 64 + lkb;
        b01[n2 * 2 + k2] =
            *(const bf16x8*)(smem + cb + 32768 + lr * 128 + (cbyte ^ ((lr & 7) << 4)));
      }
  };
  auto READB2 = [&](int cb) {
#pragma unroll
    for (int k2 = 0; k2 < 2; ++k2) {
      int lr = wn * 48 + 32 + l15;
      int cbyte = k2 * 64 + lkb;
      b2[k2] = *(const bf16x8*)(smem + cb + 32768 + lr * 128 + (cbyte ^ ((lr & 7) << 4)));
    }
  };
  auto Q01 = [&](int h) {                // 16 MFMA
#pragma unroll
    for (int m2 = 0; m2 < 4; ++m2)
#pragma unroll
      for (int n2 = 0; n2 < 2; ++n2)
#pragma unroll
        for (int k2 = 0; k2 < 2; ++k2)
          acc[h * 4 + m2][n2] = mfma16(aR[m2 * 2 + k2], b01[n2 * 2 + k2], acc[h * 4 + m2][n2]);
  };
  auto Q2 = [&](int h) {                 // 8 MFMA
#pragma unroll
    for (int m2 = 0; m2 < 4; ++m2)
#pragma unroll
      for (int k2 = 0; k2 < 2; ++k2)
        acc[h * 4 + m2][2] = mfma16(aR[m2 * 2 + k2], b2[k2], acc[h * 4 + m2][2]);
  };

#pragma unroll
  for (int c = 0; c < 7; ++c) STAGE(c, 0);
  STAGE(0, 1); STAGE(1, 1);
  asm volatile("s_waitcnt vmcnt(2)" ::: "memory");
  __builtin_amdgcn_s_barrier();

  for (int t = 0; t < NT; ++t) {
    const int cb = (t & 1) * BUFS;
    READA(cb, 0); READB01(cb);
    STAGE(2, t + 1); STAGE(3, t + 1);
    __builtin_amdgcn_s_barrier();
    asm volatile("s_waitcnt lgkmcnt(0)" ::: "memory");
    __builtin_amdgcn_sched_barrier(0);
    __builtin_amdgcn_s_setprio(1);
    Q01(0);
    __builtin_amdgcn_s_setprio(0);
    __builtin_amdgcn_s_barrier();
    READB2(cb);
    STAGE(4, t + 1); STAGE(5, t + 1);
    __builtin_amdgcn_s_barrier();
    asm volatile("s_waitcnt lgkmcnt(0)" ::: "memory");
    __builtin_amdgcn_sched_barrier(0);
    __builtin_amdgcn_s_setprio(1);
    Q2(0);
    __builtin_amdgcn_s_setprio(0);
    __builtin_amdgcn_s_barrier();
    READA(cb, 1);
    STAGE(6, t + 1);
    __builtin_amdgcn_s_barrier();
    asm volatile("s_waitcnt lgkmcnt(0)" ::: "memory");
    __builtin_amdgcn_sched_barrier(0);
    __builtin_amdgcn_s_setprio(1);
    Q2(1);
    __builtin_amdgcn_s_setprio(0);
    __builtin_amdgcn_s_barrier();
    STAGE(0, t + 2); STAGE(1, t + 2);
    __builtin_amdgcn_s_barrier();
    __builtin_amdgcn_s_setprio(1);
    Q01(1);
    __builtin_amdgcn_s_setprio(0);
    if (t + 2 < NT) asm volatile("s_waitcnt vmcnt(2)" ::: "memory");
    else            asm volatile("s_waitcnt vmcnt(0)" ::: "memory");
    __builtin_amdgcn_s_barrier();
  }

  const float* be = bo + (size_t)e * HDIM;
  float bv[3];
#pragma unroll
  for (int ni = 0; ni < 3; ++ni) bv[ni] = be[nt * 192 + wn * 48 + ni * 16 + l15];
#pragma unroll
  for (int mi = 0; mi < 8; ++mi)
#pragma unroll
    for (int r = 0; r < 4; ++r) {
      int row = mt * 256 + wm * 128 + mi * 16 + (lane >> 4) * 4 + r;
      if (row < ne) {
        int p = pb + row;
        int ts = pair_tok[p];            // (tok<<1)|slot
        float w = pair_w[p];
        float* sr = stage + (size_t)ts * HDIM + nt * 192 + wn * 48 + l15;
#pragma unroll
        for (int ni = 0; ni < 3; ++ni)
          sr[ni * 16] = (acc[mi][ni][r] + bv[ni]) * w;
      }
    }
}

// ---------------- combine: out[t] = stage[2t] + stage[2t+1] ----------------
__global__ __launch_bounds__(256) void combine_kernel(const float* __restrict__ stage,
                                                      float* __restrict__ out) {
  const int n4 = T_TOK * HDIM / 4;
  int i = blockIdx.x * 256 + threadIdx.x;
  int stride = gridDim.x * 256;
  const float4* s = (const float4*)stage;
  float4* o = (float4*)out;
  for (; i < n4; i += stride) {
    int t = i / (HDIM / 4);
    int h = i - t * (HDIM / 4);
    float4 a = s[(size_t)t * (HDIM / 2) + h];
    float4 b = s[(size_t)t * (HDIM / 2) + (HDIM / 4) + h];
    float4 r; r.x = a.x + b.x; r.y = a.y + b.y; r.z = a.z + b.z; r.w = a.w + b.w;
    o[i] = r;
  }
}

extern "C" void kernel_launch(void* const* d_in, const int* in_sizes, int n_in,
                              void* d_out, int out_size, void* d_ws, size_t ws_size,
                              hipStream_t stream) {
  const float* x  = (const float*)d_in[0];
  const float* Wr = (const float*)d_in[1];
  const float* Wi = (const float*)d_in[2];
  const float* bi = (const float*)d_in[3];
  const float* Wo = (const float*)d_in[4];
  const float* bo = (const float*)d_in[5];
  float* out = (float*)d_out;
  char* ws = (char*)d_ws;

  unsigned short* xb   = (unsigned short*)(ws + OFF_XB);
  unsigned short* wib  = (unsigned short*)(ws + OFF_WIB);
  unsigned short* wob  = (unsigned short*)(ws + OFF_WOB);
  unsigned short* hbuf = (unsigned short*)(ws + OFF_HBUF);
  int*   counts   = (int*)(ws + OFF_META);
  int*   basep    = (int*)(ws + OFF_META + 64);
  int*   cursor   = (int*)(ws + OFF_META + 128);
  int*   tok_e    = (int*)(ws + OFF_TOKE);
  float* tok_w    = (float*)(ws + OFF_TOKW);
  int*   pair_tok = (int*)(ws + OFF_PTOK);
  float* pair_w   = (float*)(ws + OFF_PW);
  float* stage    = (float*)(ws + OFF_STAGE);

  hipFuncSetAttribute((const void*)&gemmA_kernel,
                      hipFuncAttributeMaxDynamicSharedMemorySize, 131072);
  hipFuncSetAttribute((const void*)&gemmB_kernel,
                      hipFuncAttributeMaxDynamicSharedMemorySize, 114688);

  hipMemsetAsync(ws + OFF_META, 0, 256, stream);

  cvt_kernel<<<1024, 256, 0, stream>>>(x, xb, T_TOK * HDIM / 4);
  cvt_kernel<<<2048, 256, 0, stream>>>(Wi, wib, NEXP * FDIM * HDIM / 4);
  cvt_kernel<<<2048, 256, 0, stream>>>(Wo, wob, NEXP * HDIM * FDIM / 4);

  router_kernel<<<T_TOK / 4, 256, 0, stream>>>(x, Wr, tok_e, tok_w);
  count_kernel<<<64, 256, 0, stream>>>(tok_e, counts);
  scan_kernel<<<1, 64, 0, stream>>>(counts, basep);
  scatter_kernel<<<64, 256, 0, stream>>>(tok_e, tok_w, basep, cursor, pair_tok, pair_w);

  // 1-D grids: expert = bid & 7 -> one expert per XCD (L2-local weights)
  gemmA_kernel<<<8 * 32 * 12, 512, 131072, stream>>>(
      xb, wib, bi, counts, basep, pair_tok, hbuf);
  gemmB_kernel<<<8 * 32 * 4, 512, 114688, stream>>>(
      hbuf, wob, bo, counts, basep, pair_tok, pair_w, stage);

  combine_kernel<<<2048, 256, 0, stream>>>(stage, out);
}

// Round 4
// 377.121 us; speedup vs baseline: 1.0630x; 1.0630x over previous
//
#include <hip/hip_runtime.h>
#include <hip/hip_bf16.h>
#include <cstdint>
#include <cstddef>

// BertMoE: B=4,S=2048,H=768,F=3072,E=8,K=2. tokens T=8192, pairs=16384.
#define T_TOK 8192
#define HDIM  768
#define FDIM  3072
#define NEXP  8

typedef __attribute__((ext_vector_type(8))) __bf16 bf16x8;
typedef __attribute__((ext_vector_type(4))) float  f32x4;

static __device__ __forceinline__ f32x4 mfma16(bf16x8 a, bf16x8 b, f32x4 c) {
  return __builtin_amdgcn_mfma_f32_16x16x32_bf16(a, b, c, 0, 0, 0);
}

static __device__ __forceinline__ unsigned short f2b(float f) {
  return __builtin_bit_cast(unsigned short, (__bf16)f);
}

static __device__ __forceinline__ void gload16(const void* g, void* l) {
  __builtin_amdgcn_global_load_lds(
      (const __attribute__((address_space(1))) void*)g,
      (__attribute__((address_space(3))) void*)l, 16, 0, 0);
}

// ---------------- workspace layout (bytes) ----------------
static constexpr size_t OFF_XB   = 0;                                        // T*H bf16
static constexpr size_t OFF_WIB  = OFF_XB  + (size_t)T_TOK * HDIM * 2;       // E*F*H bf16
static constexpr size_t OFF_WOB  = OFF_WIB + (size_t)NEXP * FDIM * HDIM * 2; // E*H*F bf16
static constexpr size_t OFF_HBUF = OFF_WOB + (size_t)NEXP * HDIM * FDIM * 2; // 2T*F bf16
static constexpr size_t OFF_META = OFF_HBUF + (size_t)2 * T_TOK * FDIM * 2;
static constexpr size_t OFF_TOKE = OFF_META + 256;
static constexpr size_t OFF_TOKW = OFF_TOKE + 65536;
static constexpr size_t OFF_PTOK = OFF_TOKW + 65536;
static constexpr size_t OFF_PW   = OFF_PTOK + 65536;
// stage [16384][768] f32 = 50.33 MB: ALIASES xb+wib (dead once gemmA is done)
static constexpr size_t OFF_STAGE = 0;

// ---------------- fp32 -> bf16 convert ----------------
__global__ __launch_bounds__(256) void cvt_kernel(const float* __restrict__ s,
                                                  unsigned short* __restrict__ d, int n4) {
  int i = blockIdx.x * 256 + threadIdx.x;
  int stride = gridDim.x * 256;
  for (; i < n4; i += stride) {
    float4 v = ((const float4*)s)[i];
    ushort4 o;
    o.x = f2b(v.x); o.y = f2b(v.y); o.z = f2b(v.z); o.w = f2b(v.w);
    ((ushort4*)d)[i] = o;
  }
}

// ---------------- router: logits, top2, softmax ----------------
__global__ __launch_bounds__(256) void router_kernel(const float* __restrict__ x,
                                                     const float* __restrict__ Wr,
                                                     int* __restrict__ tok_e,
                                                     float* __restrict__ tok_w) {
  __shared__ float wr[NEXP * HDIM];
  int tid = threadIdx.x;
  for (int i = tid; i < NEXP * HDIM; i += 256) wr[i] = Wr[i];
  __syncthreads();
  int lane = tid & 63;
  int wv = tid >> 6;
  int t = blockIdx.x * 4 + wv;
  const float* xr = x + (size_t)t * HDIM;
  float p[NEXP];
#pragma unroll
  for (int e = 0; e < NEXP; ++e) p[e] = 0.f;
  for (int j = 0; j < HDIM / 64; ++j) {
    float xv = xr[j * 64 + lane];
#pragma unroll
    for (int e = 0; e < NEXP; ++e) p[e] += xv * wr[e * HDIM + j * 64 + lane];
  }
#pragma unroll
  for (int e = 0; e < NEXP; ++e) {
    float v = p[e];
    for (int off = 32; off; off >>= 1) v += __shfl_xor(v, off);
    p[e] = v;
  }
  if (lane == 0) {
    float v0 = -1e30f, v1 = -1e30f; int i0 = 0, i1 = 0;
#pragma unroll
    for (int e = 0; e < NEXP; ++e) {
      float v = p[e];
      if (v > v0) { v1 = v0; i1 = i0; v0 = v; i0 = e; }
      else if (v > v1) { v1 = v; i1 = e; }
    }
    float ew = expf(v1 - v0);
    float w0 = 1.0f / (1.0f + ew);
    float w1 = ew * w0;
    tok_e[t * 2 + 0] = i0; tok_w[t * 2 + 0] = w0;
    tok_e[t * 2 + 1] = i1; tok_w[t * 2 + 1] = w1;
  }
}

// ---------------- count / scan / scatter ----------------
__global__ __launch_bounds__(256) void count_kernel(const int* __restrict__ tok_e,
                                                    int* __restrict__ counts) {
  __shared__ int h[NEXP];
  int tid = threadIdx.x;
  if (tid < NEXP) h[tid] = 0;
  __syncthreads();
  int i = blockIdx.x * 256 + tid;
  atomicAdd(&h[tok_e[i]], 1);
  __syncthreads();
  if (tid < NEXP && h[tid] > 0) atomicAdd(&counts[tid], h[tid]);
}

__global__ void scan_kernel(const int* __restrict__ counts, int* __restrict__ base) {
  if (threadIdx.x == 0 && blockIdx.x == 0) {
    int s = 0;
    for (int e = 0; e < NEXP; ++e) { base[e] = s; s += counts[e]; }
  }
}

__global__ __launch_bounds__(256) void scatter_kernel(const int* __restrict__ tok_e,
                                                      const float* __restrict__ tok_w,
                                                      const int* __restrict__ base,
                                                      int* __restrict__ cursor,
                                                      int* __restrict__ pair_tok,
                                                      float* __restrict__ pair_w) {
  __shared__ int h[NEXP], bstart[NEXP];
  int tid = threadIdx.x;
  if (tid < NEXP) h[tid] = 0;
  __syncthreads();
  int i = blockIdx.x * 256 + tid;
  int e = tok_e[i];
  int r = atomicAdd(&h[e], 1);
  __syncthreads();
  if (tid < NEXP) bstart[tid] = (h[tid] > 0) ? atomicAdd(&cursor[tid], h[tid]) : 0;
  __syncthreads();
  int pos = base[e] + bstart[e] + r;
  pair_tok[pos] = i;          // packed (tok<<1)|slot
  pair_w[pos] = tok_w[i];
}

// ================= gemmA: H = gelu(X * Wi^T + bi) -> hbuf (bf16) =================
// 256x256 tile, BK=64, 8 waves, 4 phases/K-tile, deep-slack staging:
//   ph0(t): stage A-chunks 2,3 of t+1   (A region of buf[(t+1)&1] free since t-1)
//   ph2(t): stage B-chunks 0,1 of t+2   (all B reads of buf[t&1] done at ph1)
//   ph3(t): stage B-chunks 2,3 of t+2 + A-chunks 0,1 of t+2 (A reads done at ph2)
//   boundary: vmcnt(6)  (everything older than t+2's 6 newest loads has landed)
__global__ __launch_bounds__(512, 2) void gemmA_kernel(
    const unsigned short* __restrict__ xb, const unsigned short* __restrict__ wib,
    const float* __restrict__ bi,
    const int* __restrict__ counts, const int* __restrict__ base,
    const int* __restrict__ pair_tok, unsigned short* __restrict__ hbuf) {
  const int e = blockIdx.z;
  const int ne = counts[e];
  const int mt = blockIdx.y;
  if (mt * 256 >= ne) return;
  const int nt = blockIdx.x;
  const int pb = base[e];
  constexpr int NT = HDIM / 64;          // 12
  constexpr int BUFSZ = 65536;           // A 32KB + B 32KB

  extern __shared__ char smem[];         // 128 KB

  const int tid = threadIdx.x;
  const int lane = tid & 63;
  const int wv = tid >> 6;
  const int wm = wv >> 2;                // 0..1
  const int wn = wv & 3;                 // 0..3
  const int l15 = lane & 15;
  const int lkb = (lane >> 4) * 16;

  const int crow = tid >> 3;
  const int ck = tid & 7;
  const int swz = (ck ^ (crow & 7)) * 16;
  const char* aS[4]; const char* bS[4];
#pragma unroll
  for (int i = 0; i < 4; ++i) {
    int gr = mt * 256 + i * 64 + crow; if (gr > ne - 1) gr = ne - 1;
    int tok = pair_tok[pb + gr] >> 1;
    aS[i] = (const char*)xb + (size_t)tok * (HDIM * 2) + swz;
    int br = nt * 256 + i * 64 + crow;
    bS[i] = (const char*)wib + ((size_t)e * FDIM * HDIM + (size_t)br * HDIM) * 2 + swz;
  }

  auto STA = [&](int c, int t) {
    if (t < NT) gload16(aS[c] + t * 128,
                        smem + (size_t)((t & 1) * BUFSZ + c * 8192 + tid * 16));
  };
  auto STB = [&](int c, int t) {
    if (t < NT) gload16(bS[c] + t * 128,
                        smem + (size_t)((t & 1) * BUFSZ + 32768 + c * 8192 + tid * 16));
  };

  bf16x8 aR[8], bR0[4], bR1[4];
  f32x4 acc[8][4];
#pragma unroll
  for (int mi = 0; mi < 8; ++mi)
#pragma unroll
    for (int ni = 0; ni < 4; ++ni) acc[mi][ni] = (f32x4){0.f, 0.f, 0.f, 0.f};

  auto READA = [&](int cb, int h) {
#pragma unroll
    for (int m2 = 0; m2 < 4; ++m2)
#pragma unroll
      for (int k2 = 0; k2 < 2; ++k2) {
        int lr = wm * 128 + (h * 4 + m2) * 16 + l15;
        int cbyte = k2 * 64 + lkb;
        aR[m2 * 2 + k2] =
            *(const bf16x8*)(smem + cb + lr * 128 + (cbyte ^ ((lr & 7) << 4)));
      }
  };
  auto READB = [&](int cb, int h, bf16x8* bR) {
#pragma unroll
    for (int n2 = 0; n2 < 2; ++n2)
#pragma unroll
      for (int k2 = 0; k2 < 2; ++k2) {
        int lr = wn * 64 + (h * 2 + n2) * 16 + l15;
        int cbyte = k2 * 64 + lkb;
        bR[n2 * 2 + k2] =
            *(const bf16x8*)(smem + cb + 32768 + lr * 128 + (cbyte ^ ((lr & 7) << 4)));
      }
  };
  auto MFMAQ = [&](int qm, int qn, const bf16x8* bR) {
#pragma unroll
    for (int m2 = 0; m2 < 4; ++m2)
#pragma unroll
      for (int n2 = 0; n2 < 2; ++n2)
#pragma unroll
        for (int k2 = 0; k2 < 2; ++k2)
          acc[qm * 4 + m2][qn * 2 + n2] =
              mfma16(aR[m2 * 2 + k2], bR[n2 * 2 + k2], acc[qm * 4 + m2][qn * 2 + n2]);
  };

  // prologue: A(0),B(0) [buf0], B(1),A01(1) [buf1]; require A(0),B(0) landed
  STA(0, 0); STA(1, 0); STA(2, 0); STA(3, 0);
  STB(0, 0); STB(1, 0); STB(2, 0); STB(3, 0);
  STB(0, 1); STB(1, 1); STB(2, 1); STB(3, 1);
  STA(0, 1); STA(1, 1);
  asm volatile("s_waitcnt vmcnt(6)" ::: "memory");
  __builtin_amdgcn_s_barrier();

  for (int t = 0; t < NT; ++t) {
    const int cb = (t & 1) * BUFSZ;
    // ph0: Q00
    READA(cb, 0); READB(cb, 0, bR0);
    STA(2, t + 1); STA(3, t + 1);
    __builtin_amdgcn_s_barrier();
    asm volatile("s_waitcnt lgkmcnt(0)" ::: "memory");
    __builtin_amdgcn_sched_barrier(0);
    __builtin_amdgcn_s_setprio(1);
    MFMAQ(0, 0, bR0);
    __builtin_amdgcn_s_setprio(0);
    __builtin_amdgcn_s_barrier();
    // ph1: Q01
    READB(cb, 1, bR1);
    __builtin_amdgcn_s_barrier();
    asm volatile("s_waitcnt lgkmcnt(0)" ::: "memory");
    __builtin_amdgcn_sched_barrier(0);
    __builtin_amdgcn_s_setprio(1);
    MFMAQ(0, 1, bR1);
    __builtin_amdgcn_s_setprio(0);
    __builtin_amdgcn_s_barrier();
    // ph2: Q11
    READA(cb, 1);
    STB(0, t + 2); STB(1, t + 2);
    __builtin_amdgcn_s_barrier();
    asm volatile("s_waitcnt lgkmcnt(0)" ::: "memory");
    __builtin_amdgcn_sched_barrier(0);
    __builtin_amdgcn_s_setprio(1);
    MFMAQ(1, 1, bR1);
    __builtin_amdgcn_s_setprio(0);
    __builtin_amdgcn_s_barrier();
    // ph3: Q10
    STB(2, t + 2); STB(3, t + 2);
    STA(0, t + 2); STA(1, t + 2);
    __builtin_amdgcn_s_barrier();
    __builtin_amdgcn_s_setprio(1);
    MFMAQ(1, 0, bR0);
    __builtin_amdgcn_s_setprio(0);
    asm volatile("s_waitcnt vmcnt(6)" ::: "memory");
    __builtin_amdgcn_s_barrier();
  }

  const float* be = bi + (size_t)e * FDIM;
  float bv[4];
#pragma unroll
  for (int ni = 0; ni < 4; ++ni) bv[ni] = be[nt * 256 + wn * 64 + ni * 16 + l15];
#pragma unroll
  for (int mi = 0; mi < 8; ++mi)
#pragma unroll
    for (int r = 0; r < 4; ++r) {
      int row = mt * 256 + wm * 128 + mi * 16 + (lane >> 4) * 4 + r;
      if (row < ne) {
        unsigned short* hr = hbuf + (size_t)(pb + row) * FDIM + nt * 256 + wn * 64 + l15;
#pragma unroll
        for (int ni = 0; ni < 4; ++ni) {
          float v = acc[mi][ni][r] + bv[ni];
          v = 0.5f * v * (1.0f + erff(v * 0.70710678118654752f));
          hr[ni * 16] = f2b(v);
        }
      }
    }
}

// ================= gemmB: stage = (H * Wo^T + bo) * w  (f32) =================
// 256x192 tile, BK=64, 8 waves (2x4, per-wave 128x48), 4 phases, deep-slack staging.
__global__ __launch_bounds__(512, 2) void gemmB_kernel(
    const unsigned short* __restrict__ hbuf, const unsigned short* __restrict__ wob,
    const float* __restrict__ bo,
    const int* __restrict__ counts, const int* __restrict__ base,
    const int* __restrict__ pair_tok, const float* __restrict__ pair_w,
    float* __restrict__ stage) {
  const int e = blockIdx.z;
  const int ne = counts[e];
  const int mt = blockIdx.y;
  if (mt * 256 >= ne) return;
  const int nt = blockIdx.x;             // 0..3
  const int pb = base[e];
  constexpr int NT = FDIM / 64;          // 48
  constexpr int BUFSZ = 57344;           // A 32KB + B 24KB

  extern __shared__ char smem[];         // 112 KB

  const int tid = threadIdx.x;
  const int lane = tid & 63;
  const int wv = tid >> 6;
  const int wm = wv >> 2;                // 0..1
  const int wn = wv & 3;                 // 0..3 (48-col bands)
  const int l15 = lane & 15;
  const int lkb = (lane >> 4) * 16;

  const int crow = tid >> 3;
  const int ck = tid & 7;
  const int swz = (ck ^ (crow & 7)) * 16;
  const char* aS[4]; const char* bS[3];
#pragma unroll
  for (int i = 0; i < 4; ++i) {
    int gr = mt * 256 + i * 64 + crow; if (gr > ne - 1) gr = ne - 1;
    aS[i] = (const char*)hbuf + (size_t)(pb + gr) * (FDIM * 2) + swz;
  }
#pragma unroll
  for (int i = 0; i < 3; ++i) {
    int br = nt * 192 + i * 64 + crow;
    bS[i] = (const char*)wob + ((size_t)e * HDIM * FDIM + (size_t)br * FDIM) * 2 + swz;
  }

  auto STA = [&](int c, int t) {
    if (t < NT) gload16(aS[c] + t * 128,
                        smem + (size_t)((t & 1) * BUFSZ + c * 8192 + tid * 16));
  };
  auto STB = [&](int c, int t) {
    if (t < NT) gload16(bS[c] + t * 128,
                        smem + (size_t)((t & 1) * BUFSZ + 32768 + c * 8192 + tid * 16));
  };

  bf16x8 aR[8], b01[4], b2[2];
  f32x4 acc[8][3];
#pragma unroll
  for (int mi = 0; mi < 8; ++mi)
#pragma unroll
    for (int ni = 0; ni < 3; ++ni) acc[mi][ni] = (f32x4){0.f, 0.f, 0.f, 0.f};

  auto READA = [&](int cb, int h) {
#pragma unroll
    for (int m2 = 0; m2 < 4; ++m2)
#pragma unroll
      for (int k2 = 0; k2 < 2; ++k2) {
        int lr = wm * 128 + (h * 4 + m2) * 16 + l15;
        int cbyte = k2 * 64 + lkb;
        aR[m2 * 2 + k2] =
            *(const bf16x8*)(smem + cb + lr * 128 + (cbyte ^ ((lr & 7) << 4)));
      }
  };
  auto READB01 = [&](int cb) {
#pragma unroll
    for (int n2 = 0; n2 < 2; ++n2)
#pragma unroll
      for (int k2 = 0; k2 < 2; ++k2) {
        int lr = wn * 48 + n2 * 16 + l15;
        int cbyte = k2 * 64 + lkb;
        b01[n2 * 2 + k2] =
            *(const bf16x8*)(smem + cb + 32768 + lr * 128 + (cbyte ^ ((lr & 7) << 4)));
      }
  };
  auto READB2 = [&](int cb) {
#pragma unroll
    for (int k2 = 0; k2 < 2; ++k2) {
      int lr = wn * 48 + 32 + l15;
      int cbyte = k2 * 64 + lkb;
      b2[k2] = *(const bf16x8*)(smem + cb + 32768 + lr * 128 + (cbyte ^ ((lr & 7) << 4)));
    }
  };
  auto Q01 = [&](int h) {                // 16 MFMA
#pragma unroll
    for (int m2 = 0; m2 < 4; ++m2)
#pragma unroll
      for (int n2 = 0; n2 < 2; ++n2)
#pragma unroll
        for (int k2 = 0; k2 < 2; ++k2)
          acc[h * 4 + m2][n2] = mfma16(aR[m2 * 2 + k2], b01[n2 * 2 + k2], acc[h * 4 + m2][n2]);
  };
  auto Q2 = [&](int h) {                 // 8 MFMA
#pragma unroll
    for (int m2 = 0; m2 < 4; ++m2)
#pragma unroll
      for (int k2 = 0; k2 < 2; ++k2)
        acc[h * 4 + m2][2] = mfma16(aR[m2 * 2 + k2], b2[k2], acc[h * 4 + m2][2]);
  };

  // prologue
  STA(0, 0); STA(1, 0); STA(2, 0); STA(3, 0);
  STB(0, 0); STB(1, 0); STB(2, 0);
  STB(0, 1); STB(1, 1); STB(2, 1);
  STA(0, 1); STA(1, 1);
  asm volatile("s_waitcnt vmcnt(5)" ::: "memory");
  __builtin_amdgcn_s_barrier();

  for (int t = 0; t < NT; ++t) {
    const int cb = (t & 1) * BUFSZ;
    // ph0: Q01(0)
    READA(cb, 0); READB01(cb);
    STA(2, t + 1); STA(3, t + 1);
    __builtin_amdgcn_s_barrier();
    asm volatile("s_waitcnt lgkmcnt(0)" ::: "memory");
    __builtin_amdgcn_sched_barrier(0);
    __builtin_amdgcn_s_setprio(1);
    Q01(0);
    __builtin_amdgcn_s_setprio(0);
    __builtin_amdgcn_s_barrier();
    // ph1: Q2(0)
    READB2(cb);
    __builtin_amdgcn_s_barrier();
    asm volatile("s_waitcnt lgkmcnt(0)" ::: "memory");
    __builtin_amdgcn_sched_barrier(0);
    __builtin_amdgcn_s_setprio(1);
    Q2(0);
    __builtin_amdgcn_s_setprio(0);
    __builtin_amdgcn_s_barrier();
    // ph2: Q2(1)
    READA(cb, 1);
    STB(0, t + 2); STB(1, t + 2);
    __builtin_amdgcn_s_barrier();
    asm volatile("s_waitcnt lgkmcnt(0)" ::: "memory");
    __builtin_amdgcn_sched_barrier(0);
    __builtin_amdgcn_s_setprio(1);
    Q2(1);
    __builtin_amdgcn_s_setprio(0);
    __builtin_amdgcn_s_barrier();
    // ph3: Q01(1)
    STB(2, t + 2);
    STA(0, t + 2); STA(1, t + 2);
    __builtin_amdgcn_s_barrier();
    __builtin_amdgcn_s_setprio(1);
    Q01(1);
    __builtin_amdgcn_s_setprio(0);
    asm volatile("s_waitcnt vmcnt(5)" ::: "memory");
    __builtin_amdgcn_s_barrier();
  }

  const float* be = bo + (size_t)e * HDIM;
  float bv[3];
#pragma unroll
  for (int ni = 0; ni < 3; ++ni) bv[ni] = be[nt * 192 + wn * 48 + ni * 16 + l15];
#pragma unroll
  for (int mi = 0; mi < 8; ++mi)
#pragma unroll
    for (int r = 0; r < 4; ++r) {
      int row = mt * 256 + wm * 128 + mi * 16 + (lane >> 4) * 4 + r;
      if (row < ne) {
        int p = pb + row;
        int ts = pair_tok[p];            // (tok<<1)|slot
        float w = pair_w[p];
        float* sr = stage + (size_t)ts * HDIM + nt * 192 + wn * 48 + l15;
#pragma unroll
        for (int ni = 0; ni < 3; ++ni)
          sr[ni * 16] = (acc[mi][ni][r] + bv[ni]) * w;
      }
    }
}

// ---------------- combine: out[t] = stage[2t] + stage[2t+1] ----------------
__global__ __launch_bounds__(256) void combine_kernel(const float* __restrict__ stage,
                                                      float* __restrict__ out) {
  const int n4 = T_TOK * HDIM / 4;
  int i = blockIdx.x * 256 + threadIdx.x;
  int stride = gridDim.x * 256;
  const float4* s = (const float4*)stage;
  float4* o = (float4*)out;
  for (; i < n4; i += stride) {
    int t = i / (HDIM / 4);
    int h = i - t * (HDIM / 4);
    float4 a = s[(size_t)t * (HDIM / 2) + h];
    float4 b = s[(size_t)t * (HDIM / 2) + (HDIM / 4) + h];
    float4 r; r.x = a.x + b.x; r.y = a.y + b.y; r.z = a.z + b.z; r.w = a.w + b.w;
    o[i] = r;
  }
}

extern "C" void kernel_launch(void* const* d_in, const int* in_sizes, int n_in,
                              void* d_out, int out_size, void* d_ws, size_t ws_size,
                              hipStream_t stream) {
  const float* x  = (const float*)d_in[0];
  const float* Wr = (const float*)d_in[1];
  const float* Wi = (const float*)d_in[2];
  const float* bi = (const float*)d_in[3];
  const float* Wo = (const float*)d_in[4];
  const float* bo = (const float*)d_in[5];
  float* out = (float*)d_out;
  char* ws = (char*)d_ws;

  unsigned short* xb   = (unsigned short*)(ws + OFF_XB);
  unsigned short* wib  = (unsigned short*)(ws + OFF_WIB);
  unsigned short* wob  = (unsigned short*)(ws + OFF_WOB);
  unsigned short* hbuf = (unsigned short*)(ws + OFF_HBUF);
  int*   counts   = (int*)(ws + OFF_META);
  int*   basep    = (int*)(ws + OFF_META + 64);
  int*   cursor   = (int*)(ws + OFF_META + 128);
  int*   tok_e    = (int*)(ws + OFF_TOKE);
  float* tok_w    = (float*)(ws + OFF_TOKW);
  int*   pair_tok = (int*)(ws + OFF_PTOK);
  float* pair_w   = (float*)(ws + OFF_PW);
  float* stage    = (float*)(ws + OFF_STAGE);

  hipFuncSetAttribute((const void*)&gemmA_kernel,
                      hipFuncAttributeMaxDynamicSharedMemorySize, 131072);
  hipFuncSetAttribute((const void*)&gemmB_kernel,
                      hipFuncAttributeMaxDynamicSharedMemorySize, 114688);

  hipMemsetAsync(ws + OFF_META, 0, 256, stream);

  cvt_kernel<<<1024, 256, 0, stream>>>(x, xb, T_TOK * HDIM / 4);
  cvt_kernel<<<2048, 256, 0, stream>>>(Wi, wib, NEXP * FDIM * HDIM / 4);
  cvt_kernel<<<2048, 256, 0, stream>>>(Wo, wob, NEXP * HDIM * FDIM / 4);

  router_kernel<<<T_TOK / 4, 256, 0, stream>>>(x, Wr, tok_e, tok_w);
  count_kernel<<<64, 256, 0, stream>>>(tok_e, counts);
  scan_kernel<<<1, 64, 0, stream>>>(counts, basep);
  scatter_kernel<<<64, 256, 0, stream>>>(tok_e, tok_w, basep, cursor, pair_tok, pair_w);

  // balanced round-robin dispatch (no XCD pinning — round 3 showed it serializes)
  gemmA_kernel<<<dim3(FDIM / 256, T_TOK / 256, NEXP), 512, 131072, stream>>>(
      xb, wib, bi, counts, basep, pair_tok, hbuf);
  gemmB_kernel<<<dim3(HDIM / 192, T_TOK / 256, NEXP), 512, 114688, stream>>>(
      hbuf, wob, bo, counts, basep, pair_tok, pair_w, stage);

  combine_kernel<<<2048, 256, 0, stream>>>(stage, out);
}